// Round 19
// baseline (363.770 us; speedup 1.0000x reference)
//
#include <hip/hip_runtime.h>
#include <math.h>

#define NB   8192
#define TLEN 100
#define SEQ  101
#define DE   36
#define DM   72
#define NT   512    // threads per block (8 waves)
#define NW   8      // waves per block
#define OPLD 104    // operand row stride (fp16 elems); mult of 8 -> 16B-aligned b128
#define OPN  10528  // 101*104 + tail slack for clamped k-tail reads (x0 weights)

// frag sets per resblock: A:4k*5n=20, B:3*7=21, C:3*5=15, D:3*5=15 -> 71
#define RB_SETS    71
#define TOTAL_SETS 142

typedef _Float16 half8v __attribute__((ext_vector_type(8)));
typedef __attribute__((ext_vector_type(4))) float f32x4;
union U16 { uint4 u; half8v h; };

#define MFMAH(a, b, c) __builtin_amdgcn_mfma_f32_16x16x32_f16((a), (b), (c), 0, 0, 0)

static __device__ __forceinline__ unsigned short f2h(float f) {
  union { _Float16 h; unsigned short u; } c;
  c.h = (_Float16)f;
  return c.u;
}
static __device__ __forceinline__ float h2f(unsigned short u) {
  union { _Float16 h; unsigned short u; } c;
  c.u = u;
  return (float)c.h;
}

struct SetupParams {
  const float* tw1[2]; const float* tw2[2]; const float* cw1[2]; const float* cw2[2];
  unsigned* ws;
};

// Pack weights into MFMA fragment order as fp16 (round-to-nearest),
// zero-padded for k >= K and n >= N.  Slot bijection: k = kstep*32 + (lane>>4)*8 + e,
// n = ntile*16 + (lane&15); dword r holds elements e=2r (lo16) and e=2r+1 (hi16).
// A- and B-operand fragments share this bijection (operand-swap safe).
__global__ void setup_kernel(SetupParams sp) {
  int s = blockIdx.x;           // set id 0..141
  int tid = threadIdx.x;        // 256
  int l = tid >> 2, r = tid & 3;
  int rb = s / RB_SETS, s2 = s % RB_SETS;
  const float* W; int K, N, ks, nt;
  if (s2 < 20)      { ks = s2 / 5;        nt = s2 % 5;        W = sp.tw1[rb]; K = SEQ; N = DM; }
  else if (s2 < 41) { int t = s2 - 20; ks = t / 7; nt = t % 7; W = sp.tw2[rb]; K = DM;  N = SEQ; }
  else if (s2 < 56) { int t = s2 - 41; ks = t / 5; nt = t % 5; W = sp.cw1[rb]; K = DM;  N = DM; }
  else              { int t = s2 - 56; ks = t / 5; nt = t % 5; W = sp.cw2[rb]; K = DM;  N = DM; }
  int g = l >> 4;
  int n = nt * 16 + (l & 15);
  int k0 = ks * 32 + g * 8 + 2 * r;
  int k1 = k0 + 1;
  float f0 = (k0 < K && n < N) ? W[k0 * N + n] : 0.f;
  float f1 = (k1 < K && n < N) ? W[k1 * N + n] : 0.f;
  union { _Float16 h; unsigned short u; } h0, h1;
  h0.h = (_Float16)f0; h1.h = (_Float16)f1;
  unsigned idx = (unsigned)s * 256u + (unsigned)l * 4u + (unsigned)r;
  sp.ws[idx] = (unsigned)h0.u | ((unsigned)h1.u << 16);
}

struct Params {
  const float *history; const int *ts; const int *target_ts; const int *task;
  const float *w_np; const float *b_np; const float *w_wp; const float *b_wp;
  const float *task_emb;
  const float *tb1[2]; const float *tb2[2]; const float *cb1[2]; const float *cb2[2];
  const float *wp_time; const float *bp_time; const float *w_head; const float *b_head;
  const uint4 *wf; float *out;
};

// N-blocked GEMM phase with 1-row-ahead LDS pipelining: wave owns up to TWO
// weight columns (register-resident) and a contiguous row range.  Row i+1's
// A-fragment ds_read_b128s are issued BEFORE row i's MFMA chain + epilogue,
// so LDS latency (~120cy) hides under compute instead of serializing the
// read->mfma->epi->read chain (the R18 accounting: ~44% of cycles are this
// latency).  Register cost: +KSTEPS*4 VGPR only (weights NOT double-buffered
// -- the R9 spill trap).  SWAP=true: D = mfma(W,x) -> lane col = x-dim.
template<int NTN, int KSTEPS, bool SWAP, typename Epi>
static __device__ __forceinline__ void gemm_phase_nb(
    const unsigned short* __restrict__ opb,
    const uint4* __restrict__ wf, int set_base, int lane,
    int r0, int nr, int c0, int nc, Epi epi) {
  const int g8 = (lane >> 4) * 8;
  const int m16 = lane & 15;
  const int c1 = (nc > 1) ? c0 + 1 : c0;
  uint4 w0[KSTEPS], w1[KSTEPS];
  #pragma unroll
  for (int ks = 0; ks < KSTEPS; ++ks) {
    w0[ks] = wf[(size_t)(set_base + ks * NTN + c0) * 64 + lane];
    w1[ks] = wf[(size_t)(set_base + ks * NTN + c1) * 64 + lane];
  }
  half8v ahc[KSTEPS];
  {
    int mrow = r0 * 16 + m16; if (mrow > SEQ - 1) mrow = SEQ - 1;
    int ab = mrow * OPLD + g8;
    #pragma unroll
    for (int ks = 0; ks < KSTEPS; ++ks) ahc[ks] = *(const half8v*)&opb[ab + ks * 32];
  }
  for (int i = 0; i < nr; ++i) {          // <=4 iterations, wave-uniform
    half8v ahn[KSTEPS];
    if (i + 1 < nr) {                     // prefetch next row while computing
      int mrow = (r0 + i + 1) * 16 + m16; if (mrow > SEQ - 1) mrow = SEQ - 1;
      int ab = mrow * OPLD + g8;
      #pragma unroll
      for (int ks = 0; ks < KSTEPS; ++ks) ahn[ks] = *(const half8v*)&opb[ab + ks * 32];
    }
    int r = r0 + i;
    f32x4 a0 = {0.f, 0.f, 0.f, 0.f};
    #pragma unroll
    for (int ks = 0; ks < KSTEPS; ++ks) {
      U16 h; h.u = w0[ks];
      a0 = SWAP ? MFMAH(h.h, ahc[ks], a0) : MFMAH(ahc[ks], h.h, a0);
    }
    epi(r, c0, a0);
    if (nc > 1) {                          // wave-uniform branch
      f32x4 a1 = {0.f, 0.f, 0.f, 0.f};
      #pragma unroll
      for (int ks = 0; ks < KSTEPS; ++ks) {
        U16 h; h.u = w1[ks];
        a1 = SWAP ? MFMAH(h.h, ahc[ks], a1) : MFMAH(ahc[ks], h.h, a1);
      }
      epi(r, c0 + 1, a1);
    }
    if (i + 1 < nr) {
      #pragma unroll
      for (int ks = 0; ks < KSTEPS; ++ks) ahc[ks] = ahn[ks];
    }
  }
}

__global__ __launch_bounds__(NT, 4) void fpfn_kernel(Params p) {
  __shared__ __align__(16) unsigned short R1[OPN];  // xT (fp16), [c][t]
  __shared__ __align__(16) unsigned short R2[OPN];  // x residual, [t][c] fp16
  __shared__ __align__(16) unsigned short R3[OPN];  // y1 [c][j] / y2 [t][j] fp16
  __shared__ float pe[640];
  __shared__ float sh[TLEN];                        // scaled history / reduce scratch
  __shared__ unsigned short datesu[TLEN * 4];

  const int tid  = threadIdx.x;
  const int b    = blockIdx.x;
  const int lane = tid & 63;
  const int wave = tid >> 6;

  // ---- zero operand buffers (pad regions must stay finite/zero) ----
  {
    uint4 z = {0, 0, 0, 0};
    uint4* z0 = (uint4*)R1;
    uint4* z1 = (uint4*)R2;
    uint4* z2 = (uint4*)R3;
    for (int i = tid; i < OPN / 8; i += NT) { z0[i] = z; z1[i] = z; z2[i] = z; }
  }

  float s = 0.f, hist_mean = 0.f;   // valid in wave 0 (used by tid 0 at the end)

  if (wave == 0) {
    // ---- robust_scale entirely in one wave (no block barriers) ----
    int t1 = lane + 64;
    bool v1 = (t1 < TLEN);
    float h0 = p.history[(size_t)b * TLEN + lane];
    float h1 = v1 ? p.history[(size_t)b * TLEN + t1] : 0.f;
    auto wred = [&](float v) -> float {
      #pragma unroll
      for (int o = 32; o > 0; o >>= 1) v += __shfl_xor(v, o, 64);
      return v;
    };
    float nz0 = (h0 != 0.f) ? 1.f : 0.f;
    float nz1 = (v1 && h1 != 0.f) ? 1.f : 0.f;
    float cnt  = wred(nz0 + nz1);
    float hsum = wred(h0 + h1);
    float safe = fmaxf(cnt, 1.f);
    float mean = hsum / safe;
    float var  = wred(nz0 * (h0 - mean) * (h0 - mean) + nz1 * (h1 - mean) * (h1 - mean)) / safe;
    float mean_z = (cnt > 0.f) ? mean : 0.f;
    float std_z  = (cnt > 0.f) ? sqrtf(var) : 0.f;
    float upper  = mean_z + 2.f * std_z;
    float c0v = fminf(fmaxf(h0, 0.f), upper);
    float c1v = fminf(fmaxf(h1, 0.f), upper);
    float m0 = (c0v != 0.f) ? 1.f : 0.f;
    float m1 = (v1 && c1v != 0.f) ? 1.f : 0.f;
    float cnt2 = wred(m0 + m1);
    float csum = wred(m0 * c0v + m1 * c1v);
    float safe2 = fmaxf(cnt2, 1.f);
    float mc = csum / safe2;
    float vc = wred(m0 * (c0v - mc) * (c0v - mc) + m1 * (c1v - mc) * (c1v - mc)) / safe2;
    float mc_z = (cnt2 > 0.f) ? mc : 0.f;
    float sc_z = (cnt2 > 0.f) ? sqrtf(vc) : 0.f;
    s = mc_z + sc_z + 1e-4f;
    hist_mean = hsum * (1.f / (float)TLEN);
    sh[lane] = fminf(fmaxf(h0 / s, 0.f), 3.f);
    if (v1) sh[t1] = fminf(fmaxf(h1 / s, 0.f), 3.f);
  } else {
    // ---- waves 1-7: positional tables + date offsets ----
    for (int idx = tid - 64; idx < 640; idx += (NT - 64)) {
      int periods, freqs, row, col;
      if (idx < 88)       { periods = 10; freqs = 4; row = idx >> 3;        col = idx & 7; }
      else if (idx < 192) { periods = 12; freqs = 4; row = (idx - 88) >> 3; col = (idx - 88) & 7; }
      else if (idx < 576) { periods = 31; freqs = 6; int r2 = idx - 192; row = r2 / 12; col = r2 - row * 12; }
      else                { periods = 7;  freqs = 4; row = (idx - 576) >> 3; col = (idx - 576) & 7; }
      int jf = (col < freqs) ? col : (col - freqs);
      float pip = (float)(3.14159265358979323846 / (double)periods);
      float ang = pip * (float)(1 << jf) * ((float)row - 1.0f);
      pe[idx] = (col < freqs) ? sinf(ang) : cosf(ang);
    }
    int t = tid - 64;
    if (t < TLEN) {
      int yr99 = p.ts[((size_t)b * TLEN + (TLEN - 1)) * 4 + 0];
      const int* tsb = p.ts + ((size_t)b * TLEN + t) * 4;
      int dy = yr99 - tsb[0]; dy = dy < 0 ? 0 : (dy > 10 ? 10 : dy);
      datesu[t * 4 + 0] = (unsigned short)(dy * 8);
      datesu[t * 4 + 1] = (unsigned short)(88  + tsb[1] * 8);
      datesu[t * 4 + 2] = (unsigned short)(192 + tsb[2] * 12);
      datesu[t * 4 + 3] = (unsigned short)(576 + tsb[3] * 8);
    }
  }
  __syncthreads();

  // ---- build x: fp16 into R2[t][j] and transposed into R1[j][t] ----
  for (int idx = tid; idx < DM * TLEN; idx += NT) {
    int j = idx / TLEN;
    int t = idx - j * TLEN;
    float sv = sh[t];
    float v;
    if (j < DE) {
      v = fmaxf(fmaf(sv, p.w_np[j], p.b_np[j]), 0.f);
    } else {
      int jj = j - DE;
      float e1 = fmaxf(fmaf(sv, p.w_wp[jj], p.b_wp[jj]), 0.f);
      float pv;
      if (jj < 8)       pv = pe[datesu[t * 4 + 0] + jj];
      else if (jj < 16) pv = pe[datesu[t * 4 + 1] + (jj - 8)];
      else if (jj < 28) pv = pe[datesu[t * 4 + 2] + (jj - 16)];
      else              pv = pe[datesu[t * 4 + 3] + (jj - 28)];
      v = e1 + pv;
    }
    unsigned short hv = f2h(v);
    R1[j * OPLD + t] = hv;
    R2[t * OPLD + j] = hv;
  }
  if (tid < DM) {  // target row t=100
    int tk = p.task[b];
    float te = p.task_emb[tk * DE + (tid < DE ? tid : tid - DE)];
    float v = te;
    if (tid >= DE) {
      int jj = tid - DE;
      const int* tt = p.target_ts + (size_t)b * 5;
      int yr99 = p.ts[((size_t)b * TLEN + (TLEN - 1)) * 4 + 0];
      int dy = yr99 - tt[0]; dy = dy < 0 ? 0 : (dy > 10 ? 10 : dy);
      float qv;
      if (jj < 8)       qv = pe[dy * 8 + jj];
      else if (jj < 16) qv = pe[88  + tt[1] * 8  + (jj - 8)];
      else if (jj < 28) qv = pe[192 + tt[2] * 12 + (jj - 16)];
      else              qv = pe[576 + tt[3] * 8  + (jj - 28)];
      v = te + qv;
    }
    unsigned short hv = f2h(v);
    R1[tid * OPLD + (SEQ - 1)] = hv;
    R2[(SEQ - 1) * OPLD + tid] = hv;
  }
  __syncthreads();

  const int m16 = lane & 15;
  const int rowb = (lane >> 4) * 4;

  // ---- static per-wave N-blocked schedules (wave-uniform arithmetic) ----
  int Ar0, Anr, Ac0, Anc;
  if (wave < 6) { Ac0 = (wave / 3) * 2; Anc = 2; int sub = wave % 3; Ar0 = sub * 2; Anr = (sub < 2) ? 2 : 1; }
  else          { Ac0 = 4; Anc = 1; int sub = wave - 6; Ar0 = sub * 3; Anr = sub ? 2 : 3; }
  int Br0, Bnr, Bc0, Bnc;
  { int pr = wave >> 1; Bc0 = pr * 2; Bnc = (pr < 3) ? 2 : 1; int sub = wave & 1; Br0 = sub * 3; Bnr = sub ? 2 : 3; }
  int Cr0, Cnr, Cc0, Cnc;
  if (wave < 6) { Cc0 = (wave / 3) * 2; Cnc = 2; int sub = wave % 3; Cr0 = sub * 2; Cnr = (sub < 2) ? 2 : 3; }
  else          { Cc0 = 4; Cnc = 1; int sub = wave - 6; Cr0 = sub * 4; Cnr = sub ? 3 : 4; }

  #pragma unroll 1
  for (int rb = 0; rb < 2; ++rb) {
    const int base = rb * RB_SETS;
    const float* tb1 = p.tb1[rb]; const float* tb2 = p.tb2[rb];
    const float* cb1 = p.cb1[rb]; const float* cb2 = p.cb2[rb];

    // ---- A (SWAP): y1[c][j] = relu(tb1[j] + sum_t xT[c][t] tw1[t][j]);
    //      src R1(xT) -> dst R3(y1 as [c][j]) ----
    gemm_phase_nb<5, 4, true>(R1, p.wf, base + 0, lane, Ar0, Anr, Ac0, Anc,
      [&](int mt, int nt, f32x4 a) {
        int c  = mt * 16 + m16;
        int j0 = nt * 16 + rowb;
        if (c < DM && j0 < DM) {
          float4 b4 = *(const float4*)&tb1[j0];
          ushort4 hx;
          hx.x = f2h(fmaxf(a[0] + b4.x, 0.f));
          hx.y = f2h(fmaxf(a[1] + b4.y, 0.f));
          hx.z = f2h(fmaxf(a[2] + b4.z, 0.f));
          hx.w = f2h(fmaxf(a[3] + b4.w, 0.f));
          *(ushort4*)&R3[c * OPLD + j0] = hx;
        }
      });
    __syncthreads();

    // ---- B (no swap): x[t][c] += tb2[t] + sum_j y1[c][j] tw2[j][t];
    //      src R3(y1), x update in R2 ----
    gemm_phase_nb<7, 3, false>(R3, p.wf, base + 20, lane, Br0, Bnr, Bc0, Bnc,
      [&](int mt, int nt, f32x4 a) {
        int t  = nt * 16 + m16;
        int c0 = mt * 16 + rowb;
        if (t < SEQ && c0 < DM) {        // c0 mult of 4; DM mult of 4 -> no straddle
          float bias = tb2[t];
          ushort4 xo = *(const ushort4*)&R2[t * OPLD + c0];
          ushort4 hx;
          hx.x = f2h(h2f(xo.x) + a[0] + bias);
          hx.y = f2h(h2f(xo.y) + a[1] + bias);
          hx.z = f2h(h2f(xo.z) + a[2] + bias);
          hx.w = f2h(h2f(xo.w) + a[3] + bias);
          *(ushort4*)&R2[t * OPLD + c0] = hx;
        }
      });
    __syncthreads();

    // ---- C (SWAP): y2[t][j] = relu(cb1[j] + sum_c x[t][c] cw1[c][j]);
    //      src R2(x) -> dst R3(y2 as [t][j]) ----
    gemm_phase_nb<5, 3, true>(R2, p.wf, base + 41, lane, Cr0, Cnr, Cc0, Cnc,
      [&](int mt, int nt, f32x4 a) {
        int t  = mt * 16 + m16;
        int j0 = nt * 16 + rowb;
        if (t < SEQ && j0 < DM) {
          float4 b4 = *(const float4*)&cb1[j0];
          ushort4 hx;
          hx.x = f2h(fmaxf(a[0] + b4.x, 0.f));
          hx.y = f2h(fmaxf(a[1] + b4.y, 0.f));
          hx.z = f2h(fmaxf(a[2] + b4.z, 0.f));
          hx.w = f2h(fmaxf(a[3] + b4.w, 0.f));
          *(ushort4*)&R3[t * OPLD + j0] = hx;
        }
      });
    __syncthreads();

    // ---- D (SWAP): x[t][c] += cb2[c] + sum_j y2[t][j] cw2[j][c];
    //      src R3(y2) -> R2 rmw (ushort4) + R1 xT (4 scalar) ----
    gemm_phase_nb<5, 3, true>(R3, p.wf, base + 56, lane, Cr0, Cnr, Cc0, Cnc,
      [&](int mt, int nt, f32x4 a) {
        int t  = mt * 16 + m16;
        int c0 = nt * 16 + rowb;
        if (t < SEQ && c0 < DM) {
          float4 cb4 = *(const float4*)&cb2[c0];
          ushort4 xo = *(const ushort4*)&R2[t * OPLD + c0];
          ushort4 hx;
          hx.x = f2h(h2f(xo.x) + a[0] + cb4.x);
          hx.y = f2h(h2f(xo.y) + a[1] + cb4.y);
          hx.z = f2h(h2f(xo.z) + a[2] + cb4.z);
          hx.w = f2h(h2f(xo.w) + a[3] + cb4.w);
          *(ushort4*)&R2[t * OPLD + c0] = hx;
          R1[(c0 + 0) * OPLD + t] = hx.x;   // xT for next resblock's A
          R1[(c0 + 1) * OPLD + t] = hx.y;
          R1[(c0 + 2) * OPLD + t] = hx.z;
          R1[(c0 + 3) * OPLD + t] = hx.w;
        }
      });
    __syncthreads();
  }

  // ---- head, fully parallel over 512 threads:
  //      y = relu(S + bp*SW + b_head), S = sum_{t,c} x[t][c] wp[t] wh[c],
  //      SW = sum_c wh[c]  (algebraic refactor of (x^T wp + bp) . wh) ----
  {
    float part = 0.f;
    for (int i = tid; i < SEQ * DM; i += NT) {
      int t = i / DM;
      int c = i - t * DM;
      part = fmaf(h2f(R2[t * OPLD + c]) * p.wp_time[t], p.w_head[c], part);
    }
    float part2 = (tid < DM) ? p.w_head[tid] : 0.f;
    #pragma unroll
    for (int o = 32; o > 0; o >>= 1) {
      part  += __shfl_xor(part,  o, 64);
      part2 += __shfl_xor(part2, o, 64);
    }
    __syncthreads();   // sh[] free for reuse after build-x
    if (lane == 0) { sh[wave] = part; sh[8 + wave] = part2; }
    __syncthreads();
    if (tid == 0) {
      float S = 0.f, SW = 0.f;
      #pragma unroll
      for (int w = 0; w < NW; ++w) { S += sh[w]; SW += sh[8 + w]; }
      float yv = fmaxf(S + p.bp_time[0] * SW + p.b_head[0], 0.f);
      p.out[b]      = yv * s + hist_mean;
      p.out[NB + b] = s;
    }
  }
}

extern "C" void kernel_launch(void* const* d_in, const int* in_sizes, int n_in,
                              void* d_out, int out_size, void* d_ws, size_t ws_size,
                              hipStream_t stream) {
  (void)in_sizes; (void)n_in; (void)out_size; (void)ws_size;

  SetupParams sp;
  sp.tw1[0] = (const float*)d_in[9];  sp.tw2[0] = (const float*)d_in[11];
  sp.cw1[0] = (const float*)d_in[13]; sp.cw2[0] = (const float*)d_in[15];
  sp.tw1[1] = (const float*)d_in[17]; sp.tw2[1] = (const float*)d_in[19];
  sp.cw1[1] = (const float*)d_in[21]; sp.cw2[1] = (const float*)d_in[23];
  sp.ws = (unsigned*)d_ws;
  hipLaunchKernelGGL(setup_kernel, dim3(TOTAL_SETS), dim3(256), 0, stream, sp);

  Params p;
  p.history   = (const float*)d_in[0];
  p.ts        = (const int*)  d_in[1];
  p.target_ts = (const int*)  d_in[2];
  p.task      = (const int*)  d_in[3];
  p.w_np = (const float*)d_in[4];  p.b_np = (const float*)d_in[5];
  p.w_wp = (const float*)d_in[6];  p.b_wp = (const float*)d_in[7];
  p.task_emb = (const float*)d_in[8];
  p.tb1[0] = (const float*)d_in[10]; p.tb2[0] = (const float*)d_in[12];
  p.cb1[0] = (const float*)d_in[14]; p.cb2[0] = (const float*)d_in[16];
  p.tb1[1] = (const float*)d_in[18]; p.tb2[1] = (const float*)d_in[20];
  p.cb1[1] = (const float*)d_in[22]; p.cb2[1] = (const float*)d_in[24];
  p.wp_time = (const float*)d_in[25]; p.bp_time = (const float*)d_in[26];
  p.w_head  = (const float*)d_in[27]; p.b_head  = (const float*)d_in[28];
  p.wf  = (const uint4*)d_ws;
  p.out = (float*)d_out;
  hipLaunchKernelGGL(fpfn_kernel, dim3(NB), dim3(NT), 0, stream, p);
}

// Round 20
// 353.446 us; speedup vs baseline: 1.0292x; 1.0292x over previous
//
#include <hip/hip_runtime.h>
#include <math.h>

#define NB   8192
#define TLEN 100
#define SEQ  101
#define DE   36
#define DM   72
#define NT   512    // threads per block (8 waves)
#define NW   8      // waves per block
#define OPLD 104    // operand row stride (fp16 elems); mult of 8 -> 16B-aligned b128
#define OPN  10528  // 101*104 + tail slack for clamped k-tail reads (x0 weights)

// frag sets per resblock: A:4k*5n=20, B:3*7=21, C:3*5=15, D:3*5=15 -> 71
#define RB_SETS    71
#define TOTAL_SETS 142

typedef _Float16 half8v __attribute__((ext_vector_type(8)));
typedef __attribute__((ext_vector_type(4))) float f32x4;
union U16 { uint4 u; half8v h; };

#define MFMAH(a, b, c) __builtin_amdgcn_mfma_f32_16x16x32_f16((a), (b), (c), 0, 0, 0)

static __device__ __forceinline__ unsigned short f2h(float f) {
  union { _Float16 h; unsigned short u; } c;
  c.h = (_Float16)f;
  return c.u;
}
static __device__ __forceinline__ float h2f(unsigned short u) {
  union { _Float16 h; unsigned short u; } c;
  c.u = u;
  return (float)c.h;
}

struct SetupParams {
  const float* tw1[2]; const float* tw2[2]; const float* cw1[2]; const float* cw2[2];
  unsigned* ws;
};

// Pack weights into MFMA fragment order as fp16 (round-to-nearest),
// zero-padded for k >= K and n >= N.  Slot bijection: k = kstep*32 + (lane>>4)*8 + e,
// n = ntile*16 + (lane&15); dword r holds elements e=2r (lo16) and e=2r+1 (hi16).
// A- and B-operand fragments share this bijection (operand-swap safe).
__global__ void setup_kernel(SetupParams sp) {
  int s = blockIdx.x;           // set id 0..141
  int tid = threadIdx.x;        // 256
  int l = tid >> 2, r = tid & 3;
  int rb = s / RB_SETS, s2 = s % RB_SETS;
  const float* W; int K, N, ks, nt;
  if (s2 < 20)      { ks = s2 / 5;        nt = s2 % 5;        W = sp.tw1[rb]; K = SEQ; N = DM; }
  else if (s2 < 41) { int t = s2 - 20; ks = t / 7; nt = t % 7; W = sp.tw2[rb]; K = DM;  N = SEQ; }
  else if (s2 < 56) { int t = s2 - 41; ks = t / 5; nt = t % 5; W = sp.cw1[rb]; K = DM;  N = DM; }
  else              { int t = s2 - 56; ks = t / 5; nt = t % 5; W = sp.cw2[rb]; K = DM;  N = DM; }
  int g = l >> 4;
  int n = nt * 16 + (l & 15);
  int k0 = ks * 32 + g * 8 + 2 * r;
  int k1 = k0 + 1;
  float f0 = (k0 < K && n < N) ? W[k0 * N + n] : 0.f;
  float f1 = (k1 < K && n < N) ? W[k1 * N + n] : 0.f;
  union { _Float16 h; unsigned short u; } h0, h1;
  h0.h = (_Float16)f0; h1.h = (_Float16)f1;
  unsigned idx = (unsigned)s * 256u + (unsigned)l * 4u + (unsigned)r;
  sp.ws[idx] = (unsigned)h0.u | ((unsigned)h1.u << 16);
}

struct Params {
  const float *history; const int *ts; const int *target_ts; const int *task;
  const float *w_np; const float *b_np; const float *w_wp; const float *b_wp;
  const float *task_emb;
  const float *tb1[2]; const float *tb2[2]; const float *cb1[2]; const float *cb2[2];
  const float *wp_time; const float *bp_time; const float *w_head; const float *b_head;
  const uint4 *wf; float *out;
};

// N-blocked GEMM phase (R18 form, no prefetch -- every added-instruction
// latency fix R9/R16/R19 lost more VALU issue than it hid): wave owns up to
// TWO register-resident weight columns and a contiguous row range; each
// A-fragment ds_read_b128 is reused for both columns.  Static wave-uniform
// schedule, no dead MFMA work.  SWAP=true: D = mfma(W,x) -> lane col = x-dim.
template<int NTN, int KSTEPS, bool SWAP, typename Epi>
static __device__ __forceinline__ void gemm_phase_nb(
    const unsigned short* __restrict__ opb,
    const uint4* __restrict__ wf, int set_base, int lane,
    int r0, int nr, int c0, int nc, Epi epi) {
  const int g8 = (lane >> 4) * 8;
  const int m16 = lane & 15;
  const int c1 = (nc > 1) ? c0 + 1 : c0;
  uint4 w0[KSTEPS], w1[KSTEPS];
  #pragma unroll
  for (int ks = 0; ks < KSTEPS; ++ks) {
    w0[ks] = wf[(size_t)(set_base + ks * NTN + c0) * 64 + lane];
    w1[ks] = wf[(size_t)(set_base + ks * NTN + c1) * 64 + lane];
  }
  for (int i = 0; i < nr; ++i) {          // <=4 iterations, wave-uniform
    int r = r0 + i;
    int mrow = r * 16 + m16; if (mrow > SEQ - 1) mrow = SEQ - 1;
    int ab = mrow * OPLD + g8;
    half8v ah[KSTEPS];
    #pragma unroll
    for (int ks = 0; ks < KSTEPS; ++ks) ah[ks] = *(const half8v*)&opb[ab + ks * 32];
    f32x4 a0 = {0.f, 0.f, 0.f, 0.f};
    #pragma unroll
    for (int ks = 0; ks < KSTEPS; ++ks) {
      U16 h; h.u = w0[ks];
      a0 = SWAP ? MFMAH(h.h, ah[ks], a0) : MFMAH(ah[ks], h.h, a0);
    }
    epi(r, c0, a0);
    if (nc > 1) {                          // wave-uniform branch
      f32x4 a1 = {0.f, 0.f, 0.f, 0.f};
      #pragma unroll
      for (int ks = 0; ks < KSTEPS; ++ks) {
        U16 h; h.u = w1[ks];
        a1 = SWAP ? MFMAH(h.h, ah[ks], a1) : MFMAH(ah[ks], h.h, a1);
      }
      epi(r, c0 + 1, a1);
    }
  }
}

__global__ __launch_bounds__(NT, 4) void fpfn_kernel(Params p) {
  __shared__ __align__(16) unsigned short R1[OPN];  // xT (fp16), [c][t]
  __shared__ __align__(16) unsigned short R2[OPN];  // x residual, [t][c] fp16
  __shared__ __align__(16) unsigned short R3[OPN];  // y1 [c][j] / y2 [t][j] fp16
  __shared__ float pe[640];
  __shared__ float sh[TLEN];                        // scaled history / reduce scratch
  __shared__ unsigned short datesu[TLEN * 4];

  const int tid  = threadIdx.x;
  const int b    = blockIdx.x;
  const int lane = tid & 63;
  const int wave = tid >> 6;

  // ---- zero operand buffers (pad regions must stay finite/zero) ----
  {
    uint4 z = {0, 0, 0, 0};
    uint4* z0 = (uint4*)R1;
    uint4* z1 = (uint4*)R2;
    uint4* z2 = (uint4*)R3;
    for (int i = tid; i < OPN / 8; i += NT) { z0[i] = z; z1[i] = z; z2[i] = z; }
  }

  float s = 0.f, hist_mean = 0.f;   // valid in wave 0 (used by tid 0 at the end)

  if (wave == 0) {
    // ---- robust_scale entirely in one wave (no block barriers) ----
    int t1 = lane + 64;
    bool v1 = (t1 < TLEN);
    float h0 = p.history[(size_t)b * TLEN + lane];
    float h1 = v1 ? p.history[(size_t)b * TLEN + t1] : 0.f;
    auto wred = [&](float v) -> float {
      #pragma unroll
      for (int o = 32; o > 0; o >>= 1) v += __shfl_xor(v, o, 64);
      return v;
    };
    float nz0 = (h0 != 0.f) ? 1.f : 0.f;
    float nz1 = (v1 && h1 != 0.f) ? 1.f : 0.f;
    float cnt  = wred(nz0 + nz1);
    float hsum = wred(h0 + h1);
    float safe = fmaxf(cnt, 1.f);
    float mean = hsum / safe;
    float var  = wred(nz0 * (h0 - mean) * (h0 - mean) + nz1 * (h1 - mean) * (h1 - mean)) / safe;
    float mean_z = (cnt > 0.f) ? mean : 0.f;
    float std_z  = (cnt > 0.f) ? sqrtf(var) : 0.f;
    float upper  = mean_z + 2.f * std_z;
    float c0v = fminf(fmaxf(h0, 0.f), upper);
    float c1v = fminf(fmaxf(h1, 0.f), upper);
    float m0 = (c0v != 0.f) ? 1.f : 0.f;
    float m1 = (v1 && c1v != 0.f) ? 1.f : 0.f;
    float cnt2 = wred(m0 + m1);
    float csum = wred(m0 * c0v + m1 * c1v);
    float safe2 = fmaxf(cnt2, 1.f);
    float mc = csum / safe2;
    float vc = wred(m0 * (c0v - mc) * (c0v - mc) + m1 * (c1v - mc) * (c1v - mc)) / safe2;
    float mc_z = (cnt2 > 0.f) ? mc : 0.f;
    float sc_z = (cnt2 > 0.f) ? sqrtf(vc) : 0.f;
    s = mc_z + sc_z + 1e-4f;
    hist_mean = hsum * (1.f / (float)TLEN);
    sh[lane] = fminf(fmaxf(h0 / s, 0.f), 3.f);
    if (v1) sh[t1] = fminf(fmaxf(h1 / s, 0.f), 3.f);
  } else {
    // ---- waves 1-7: positional tables + date offsets ----
    for (int idx = tid - 64; idx < 640; idx += (NT - 64)) {
      int periods, freqs, row, col;
      if (idx < 88)       { periods = 10; freqs = 4; row = idx >> 3;        col = idx & 7; }
      else if (idx < 192) { periods = 12; freqs = 4; row = (idx - 88) >> 3; col = (idx - 88) & 7; }
      else if (idx < 576) { periods = 31; freqs = 6; int r2 = idx - 192; row = r2 / 12; col = r2 - row * 12; }
      else                { periods = 7;  freqs = 4; row = (idx - 576) >> 3; col = (idx - 576) & 7; }
      int jf = (col < freqs) ? col : (col - freqs);
      float pip = (float)(3.14159265358979323846 / (double)periods);
      float ang = pip * (float)(1 << jf) * ((float)row - 1.0f);
      pe[idx] = (col < freqs) ? sinf(ang) : cosf(ang);
    }
    int t = tid - 64;
    if (t < TLEN) {
      int yr99 = p.ts[((size_t)b * TLEN + (TLEN - 1)) * 4 + 0];
      const int* tsb = p.ts + ((size_t)b * TLEN + t) * 4;
      int dy = yr99 - tsb[0]; dy = dy < 0 ? 0 : (dy > 10 ? 10 : dy);
      datesu[t * 4 + 0] = (unsigned short)(dy * 8);
      datesu[t * 4 + 1] = (unsigned short)(88  + tsb[1] * 8);
      datesu[t * 4 + 2] = (unsigned short)(192 + tsb[2] * 12);
      datesu[t * 4 + 3] = (unsigned short)(576 + tsb[3] * 8);
    }
  }
  __syncthreads();

  // ---- build x: fp16 into R2[t][j] and transposed into R1[j][t] ----
  for (int idx = tid; idx < DM * TLEN; idx += NT) {
    int j = idx / TLEN;
    int t = idx - j * TLEN;
    float sv = sh[t];
    float v;
    if (j < DE) {
      v = fmaxf(fmaf(sv, p.w_np[j], p.b_np[j]), 0.f);
    } else {
      int jj = j - DE;
      float e1 = fmaxf(fmaf(sv, p.w_wp[jj], p.b_wp[jj]), 0.f);
      float pv;
      if (jj < 8)       pv = pe[datesu[t * 4 + 0] + jj];
      else if (jj < 16) pv = pe[datesu[t * 4 + 1] + (jj - 8)];
      else if (jj < 28) pv = pe[datesu[t * 4 + 2] + (jj - 16)];
      else              pv = pe[datesu[t * 4 + 3] + (jj - 28)];
      v = e1 + pv;
    }
    unsigned short hv = f2h(v);
    R1[j * OPLD + t] = hv;
    R2[t * OPLD + j] = hv;
  }
  if (tid < DM) {  // target row t=100
    int tk = p.task[b];
    float te = p.task_emb[tk * DE + (tid < DE ? tid : tid - DE)];
    float v = te;
    if (tid >= DE) {
      int jj = tid - DE;
      const int* tt = p.target_ts + (size_t)b * 5;
      int yr99 = p.ts[((size_t)b * TLEN + (TLEN - 1)) * 4 + 0];
      int dy = yr99 - tt[0]; dy = dy < 0 ? 0 : (dy > 10 ? 10 : dy);
      float qv;
      if (jj < 8)       qv = pe[dy * 8 + jj];
      else if (jj < 16) qv = pe[88  + tt[1] * 8  + (jj - 8)];
      else if (jj < 28) qv = pe[192 + tt[2] * 12 + (jj - 16)];
      else              qv = pe[576 + tt[3] * 8  + (jj - 28)];
      v = te + qv;
    }
    unsigned short hv = f2h(v);
    R1[tid * OPLD + (SEQ - 1)] = hv;
    R2[(SEQ - 1) * OPLD + tid] = hv;
  }
  __syncthreads();

  const int m16 = lane & 15;
  const int rowb = (lane >> 4) * 4;

  // ---- static per-wave N-blocked schedules (wave-uniform arithmetic) ----
  int Ar0, Anr, Ac0, Anc;
  if (wave < 6) { Ac0 = (wave / 3) * 2; Anc = 2; int sub = wave % 3; Ar0 = sub * 2; Anr = (sub < 2) ? 2 : 1; }
  else          { Ac0 = 4; Anc = 1; int sub = wave - 6; Ar0 = sub * 3; Anr = sub ? 2 : 3; }
  int Br0, Bnr, Bc0, Bnc;
  { int pr = wave >> 1; Bc0 = pr * 2; Bnc = (pr < 3) ? 2 : 1; int sub = wave & 1; Br0 = sub * 3; Bnr = sub ? 2 : 3; }
  int Cr0, Cnr, Cc0, Cnc;
  if (wave < 6) { Cc0 = (wave / 3) * 2; Cnc = 2; int sub = wave % 3; Cr0 = sub * 2; Cnr = (sub < 2) ? 2 : 3; }
  else          { Cc0 = 4; Cnc = 1; int sub = wave - 6; Cr0 = sub * 4; Cnr = sub ? 3 : 4; }

  #pragma unroll 1
  for (int rb = 0; rb < 2; ++rb) {
    const int base = rb * RB_SETS;
    const float* tb1 = p.tb1[rb]; const float* tb2 = p.tb2[rb];
    const float* cb1 = p.cb1[rb]; const float* cb2 = p.cb2[rb];

    // ---- A (SWAP): y1[c][j] = relu(tb1[j] + sum_t xT[c][t] tw1[t][j]);
    //      src R1(xT) -> dst R3(y1 as [c][j]) ----
    gemm_phase_nb<5, 4, true>(R1, p.wf, base + 0, lane, Ar0, Anr, Ac0, Anc,
      [&](int mt, int nt, f32x4 a) {
        int c  = mt * 16 + m16;
        int j0 = nt * 16 + rowb;
        if (c < DM && j0 < DM) {
          float4 b4 = *(const float4*)&tb1[j0];
          ushort4 hx;
          hx.x = f2h(fmaxf(a[0] + b4.x, 0.f));
          hx.y = f2h(fmaxf(a[1] + b4.y, 0.f));
          hx.z = f2h(fmaxf(a[2] + b4.z, 0.f));
          hx.w = f2h(fmaxf(a[3] + b4.w, 0.f));
          *(ushort4*)&R3[c * OPLD + j0] = hx;
        }
      });
    __syncthreads();

    // ---- B (no swap): x[t][c] += tb2[t] + sum_j y1[c][j] tw2[j][t];
    //      src R3(y1), x update in R2 ----
    gemm_phase_nb<7, 3, false>(R3, p.wf, base + 20, lane, Br0, Bnr, Bc0, Bnc,
      [&](int mt, int nt, f32x4 a) {
        int t  = nt * 16 + m16;
        int c0 = mt * 16 + rowb;
        if (t < SEQ && c0 < DM) {        // c0 mult of 4; DM mult of 4 -> no straddle
          float bias = tb2[t];
          ushort4 xo = *(const ushort4*)&R2[t * OPLD + c0];
          ushort4 hx;
          hx.x = f2h(h2f(xo.x) + a[0] + bias);
          hx.y = f2h(h2f(xo.y) + a[1] + bias);
          hx.z = f2h(h2f(xo.z) + a[2] + bias);
          hx.w = f2h(h2f(xo.w) + a[3] + bias);
          *(ushort4*)&R2[t * OPLD + c0] = hx;
        }
      });
    __syncthreads();

    // ---- C (SWAP): y2[t][j] = relu(cb1[j] + sum_c x[t][c] cw1[c][j]);
    //      src R2(x) -> dst R3(y2 as [t][j]) ----
    gemm_phase_nb<5, 3, true>(R2, p.wf, base + 41, lane, Cr0, Cnr, Cc0, Cnc,
      [&](int mt, int nt, f32x4 a) {
        int t  = mt * 16 + m16;
        int j0 = nt * 16 + rowb;
        if (t < SEQ && j0 < DM) {
          float4 b4 = *(const float4*)&cb1[j0];
          ushort4 hx;
          hx.x = f2h(fmaxf(a[0] + b4.x, 0.f));
          hx.y = f2h(fmaxf(a[1] + b4.y, 0.f));
          hx.z = f2h(fmaxf(a[2] + b4.z, 0.f));
          hx.w = f2h(fmaxf(a[3] + b4.w, 0.f));
          *(ushort4*)&R3[t * OPLD + j0] = hx;
        }
      });
    __syncthreads();

    // ---- D (SWAP): x[t][c] += cb2[c] + sum_j y2[t][j] cw2[j][c];
    //      src R3(y2) -> R2 rmw (ushort4) + R1 xT (4 scalar) ----
    gemm_phase_nb<5, 3, true>(R3, p.wf, base + 56, lane, Cr0, Cnr, Cc0, Cnc,
      [&](int mt, int nt, f32x4 a) {
        int t  = mt * 16 + m16;
        int c0 = nt * 16 + rowb;
        if (t < SEQ && c0 < DM) {
          float4 cb4 = *(const float4*)&cb2[c0];
          ushort4 xo = *(const ushort4*)&R2[t * OPLD + c0];
          ushort4 hx;
          hx.x = f2h(h2f(xo.x) + a[0] + cb4.x);
          hx.y = f2h(h2f(xo.y) + a[1] + cb4.y);
          hx.z = f2h(h2f(xo.z) + a[2] + cb4.z);
          hx.w = f2h(h2f(xo.w) + a[3] + cb4.w);
          *(ushort4*)&R2[t * OPLD + c0] = hx;
          R1[(c0 + 0) * OPLD + t] = hx.x;   // xT for next resblock's A
          R1[(c0 + 1) * OPLD + t] = hx.y;
          R1[(c0 + 2) * OPLD + t] = hx.z;
          R1[(c0 + 3) * OPLD + t] = hx.w;
        }
      });
    __syncthreads();
  }

  // ---- head, fully parallel over 512 threads:
  //      y = relu(S + bp*SW + b_head), S = sum_{t,c} x[t][c] wp[t] wh[c],
  //      SW = sum_c wh[c]  (algebraic refactor of (x^T wp + bp) . wh;
  //      removes the serial 101-iter/72-thread + 72-iter/1-thread tail) ----
  {
    float part = 0.f;
    for (int i = tid; i < SEQ * DM; i += NT) {
      int t = i / DM;
      int c = i - t * DM;
      part = fmaf(h2f(R2[t * OPLD + c]) * p.wp_time[t], p.w_head[c], part);
    }
    float part2 = (tid < DM) ? p.w_head[tid] : 0.f;
    #pragma unroll
    for (int o = 32; o > 0; o >>= 1) {
      part  += __shfl_xor(part,  o, 64);
      part2 += __shfl_xor(part2, o, 64);
    }
    if (lane == 0) { sh[wave] = part; sh[8 + wave] = part2; }
    __syncthreads();
    if (tid == 0) {
      float S = 0.f, SW = 0.f;
      #pragma unroll
      for (int w = 0; w < NW; ++w) { S += sh[w]; SW += sh[8 + w]; }
      float yv = fmaxf(S + p.bp_time[0] * SW + p.b_head[0], 0.f);
      p.out[b]      = yv * s + hist_mean;
      p.out[NB + b] = s;
    }
  }
}

extern "C" void kernel_launch(void* const* d_in, const int* in_sizes, int n_in,
                              void* d_out, int out_size, void* d_ws, size_t ws_size,
                              hipStream_t stream) {
  (void)in_sizes; (void)n_in; (void)out_size; (void)ws_size;

  SetupParams sp;
  sp.tw1[0] = (const float*)d_in[9];  sp.tw2[0] = (const float*)d_in[11];
  sp.cw1[0] = (const float*)d_in[13]; sp.cw2[0] = (const float*)d_in[15];
  sp.tw1[1] = (const float*)d_in[17]; sp.tw2[1] = (const float*)d_in[19];
  sp.cw1[1] = (const float*)d_in[21]; sp.cw2[1] = (const float*)d_in[23];
  sp.ws = (unsigned*)d_ws;
  hipLaunchKernelGGL(setup_kernel, dim3(TOTAL_SETS), dim3(256), 0, stream, sp);

  Params p;
  p.history   = (const float*)d_in[0];
  p.ts        = (const int*)  d_in[1];
  p.target_ts = (const int*)  d_in[2];
  p.task      = (const int*)  d_in[3];
  p.w_np = (const float*)d_in[4];  p.b_np = (const float*)d_in[5];
  p.w_wp = (const float*)d_in[6];  p.b_wp = (const float*)d_in[7];
  p.task_emb = (const float*)d_in[8];
  p.tb1[0] = (const float*)d_in[10]; p.tb2[0] = (const float*)d_in[12];
  p.cb1[0] = (const float*)d_in[14]; p.cb2[0] = (const float*)d_in[16];
  p.tb1[1] = (const float*)d_in[18]; p.tb2[1] = (const float*)d_in[20];
  p.cb1[1] = (const float*)d_in[22]; p.cb2[1] = (const float*)d_in[24];
  p.wp_time = (const float*)d_in[25]; p.bp_time = (const float*)d_in[26];
  p.w_head  = (const float*)d_in[27]; p.b_head  = (const float*)d_in[28];
  p.wf  = (const uint4*)d_ws;
  p.out = (float*)d_out;
  hipLaunchKernelGGL(fpfn_kernel, dim3(NB), dim3(NT), 0, stream, p);
}

// Round 21
// 337.256 us; speedup vs baseline: 1.0786x; 1.0480x over previous
//
#include <hip/hip_runtime.h>
#include <math.h>

#define NB   8192
#define TLEN 100
#define SEQ  101
#define DE   36
#define DM   72
#define NT   512    // threads per block (8 waves)
#define NW   8      // waves per block
#define OPLD 104    // operand row stride (fp16 elems); mult of 8 -> 16B-aligned b128
#define OPN  10528  // 101*104 + tail slack for clamped k-tail reads (x0 weights)

// frag sets per resblock: A:4k*5n=20, B:3*7=21, C:3*5=15, D:3*5=15 -> 71
#define RB_SETS    71
#define TOTAL_SETS 142

typedef _Float16 half8v __attribute__((ext_vector_type(8)));
typedef __attribute__((ext_vector_type(4))) float f32x4;
union U16 { uint4 u; half8v h; };

#define MFMAH(a, b, c) __builtin_amdgcn_mfma_f32_16x16x32_f16((a), (b), (c), 0, 0, 0)

static __device__ __forceinline__ unsigned short f2h(float f) {
  union { _Float16 h; unsigned short u; } c;
  c.h = (_Float16)f;
  return c.u;
}
static __device__ __forceinline__ float h2f(unsigned short u) {
  union { _Float16 h; unsigned short u; } c;
  c.u = u;
  return (float)c.h;
}

struct SetupParams {
  const float* tw1[2]; const float* tw2[2]; const float* cw1[2]; const float* cw2[2];
  unsigned* ws;
};

// Pack weights into MFMA fragment order as fp16 (round-to-nearest),
// zero-padded for k >= K and n >= N.  Slot bijection: k = kstep*32 + (lane>>4)*8 + e,
// n = ntile*16 + (lane&15); dword r holds elements e=2r (lo16) and e=2r+1 (hi16).
// A- and B-operand fragments share this bijection (operand-swap safe).
__global__ void setup_kernel(SetupParams sp) {
  int s = blockIdx.x;           // set id 0..141
  int tid = threadIdx.x;        // 256
  int l = tid >> 2, r = tid & 3;
  int rb = s / RB_SETS, s2 = s % RB_SETS;
  const float* W; int K, N, ks, nt;
  if (s2 < 20)      { ks = s2 / 5;        nt = s2 % 5;        W = sp.tw1[rb]; K = SEQ; N = DM; }
  else if (s2 < 41) { int t = s2 - 20; ks = t / 7; nt = t % 7; W = sp.tw2[rb]; K = DM;  N = SEQ; }
  else if (s2 < 56) { int t = s2 - 41; ks = t / 5; nt = t % 5; W = sp.cw1[rb]; K = DM;  N = DM; }
  else              { int t = s2 - 56; ks = t / 5; nt = t % 5; W = sp.cw2[rb]; K = DM;  N = DM; }
  int g = l >> 4;
  int n = nt * 16 + (l & 15);
  int k0 = ks * 32 + g * 8 + 2 * r;
  int k1 = k0 + 1;
  float f0 = (k0 < K && n < N) ? W[k0 * N + n] : 0.f;
  float f1 = (k1 < K && n < N) ? W[k1 * N + n] : 0.f;
  union { _Float16 h; unsigned short u; } h0, h1;
  h0.h = (_Float16)f0; h1.h = (_Float16)f1;
  unsigned idx = (unsigned)s * 256u + (unsigned)l * 4u + (unsigned)r;
  sp.ws[idx] = (unsigned)h0.u | ((unsigned)h1.u << 16);
}

struct Params {
  const float *history; const int *ts; const int *target_ts; const int *task;
  const float *w_np; const float *b_np; const float *w_wp; const float *b_wp;
  const float *task_emb;
  const float *tb1[2]; const float *tb2[2]; const float *cb1[2]; const float *cb2[2];
  const float *wp_time; const float *bp_time; const float *w_head; const float *b_head;
  const uint4 *wf; float *out;
};

// N-blocked GEMM phase (best-known form): wave owns up to TWO register-
// resident weight columns and a contiguous row range; each A-fragment
// ds_read_b128 is reused for both columns.  Static wave-uniform schedule,
// no dead MFMA work, no prefetch (all three latency-hiding attempts
// R9/R16/R19 regressed via register pressure / added VALU issue).
// SWAP=true: D = mfma(W,x) -> lane col = x-dim, regs = weight-dim.
template<int NTN, int KSTEPS, bool SWAP, typename Epi>
static __device__ __forceinline__ void gemm_phase_nb(
    const unsigned short* __restrict__ opb,
    const uint4* __restrict__ wf, int set_base, int lane,
    int r0, int nr, int c0, int nc, Epi epi) {
  const int g8 = (lane >> 4) * 8;
  const int m16 = lane & 15;
  const int c1 = (nc > 1) ? c0 + 1 : c0;
  uint4 w0[KSTEPS], w1[KSTEPS];
  #pragma unroll
  for (int ks = 0; ks < KSTEPS; ++ks) {
    w0[ks] = wf[(size_t)(set_base + ks * NTN + c0) * 64 + lane];
    w1[ks] = wf[(size_t)(set_base + ks * NTN + c1) * 64 + lane];
  }
  for (int i = 0; i < nr; ++i) {          // <=4 iterations, wave-uniform
    int r = r0 + i;
    int mrow = r * 16 + m16; if (mrow > SEQ - 1) mrow = SEQ - 1;
    int ab = mrow * OPLD + g8;
    half8v ah[KSTEPS];
    #pragma unroll
    for (int ks = 0; ks < KSTEPS; ++ks) ah[ks] = *(const half8v*)&opb[ab + ks * 32];
    f32x4 a0 = {0.f, 0.f, 0.f, 0.f};
    #pragma unroll
    for (int ks = 0; ks < KSTEPS; ++ks) {
      U16 h; h.u = w0[ks];
      a0 = SWAP ? MFMAH(h.h, ah[ks], a0) : MFMAH(ah[ks], h.h, a0);
    }
    epi(r, c0, a0);
    if (nc > 1) {                          // wave-uniform branch
      f32x4 a1 = {0.f, 0.f, 0.f, 0.f};
      #pragma unroll
      for (int ks = 0; ks < KSTEPS; ++ks) {
        U16 h; h.u = w1[ks];
        a1 = SWAP ? MFMAH(h.h, ah[ks], a1) : MFMAH(ah[ks], h.h, a1);
      }
      epi(r, c0 + 1, a1);
    }
  }
}

__global__ __launch_bounds__(NT, 4) void fpfn_kernel(Params p) {
  __shared__ __align__(16) unsigned short R1[OPN];  // xT (fp16), [c][t]
  __shared__ __align__(16) unsigned short R2[OPN];  // x residual, [t][c] fp16
  __shared__ __align__(16) unsigned short R3[OPN];  // y1 [c][j] / y2 [t][j] fp16
  __shared__ float pe[640];
  __shared__ float sh[TLEN];                        // scaled history, later head partials
  __shared__ unsigned short datesu[TLEN * 4];

  const int tid  = threadIdx.x;
  const int b    = blockIdx.x;
  const int lane = tid & 63;
  const int wave = tid >> 6;

  // ---- zero operand buffers (pad regions must stay finite/zero) ----
  {
    uint4 z = {0, 0, 0, 0};
    uint4* z0 = (uint4*)R1;
    uint4* z1 = (uint4*)R2;
    uint4* z2 = (uint4*)R3;
    for (int i = tid; i < OPN / 8; i += NT) { z0[i] = z; z1[i] = z; z2[i] = z; }
  }

  float s = 0.f, hist_mean = 0.f;   // valid in wave 0 (used by tid 0 at the end)

  if (wave == 0) {
    // ---- robust_scale entirely in one wave (no block barriers) ----
    int t1 = lane + 64;
    bool v1 = (t1 < TLEN);
    float h0 = p.history[(size_t)b * TLEN + lane];
    float h1 = v1 ? p.history[(size_t)b * TLEN + t1] : 0.f;
    auto wred = [&](float v) -> float {
      #pragma unroll
      for (int o = 32; o > 0; o >>= 1) v += __shfl_xor(v, o, 64);
      return v;
    };
    float nz0 = (h0 != 0.f) ? 1.f : 0.f;
    float nz1 = (v1 && h1 != 0.f) ? 1.f : 0.f;
    float cnt  = wred(nz0 + nz1);
    float hsum = wred(h0 + h1);
    float safe = fmaxf(cnt, 1.f);
    float mean = hsum / safe;
    float var  = wred(nz0 * (h0 - mean) * (h0 - mean) + nz1 * (h1 - mean) * (h1 - mean)) / safe;
    float mean_z = (cnt > 0.f) ? mean : 0.f;
    float std_z  = (cnt > 0.f) ? sqrtf(var) : 0.f;
    float upper  = mean_z + 2.f * std_z;
    float c0v = fminf(fmaxf(h0, 0.f), upper);
    float c1v = fminf(fmaxf(h1, 0.f), upper);
    float m0 = (c0v != 0.f) ? 1.f : 0.f;
    float m1 = (v1 && c1v != 0.f) ? 1.f : 0.f;
    float cnt2 = wred(m0 + m1);
    float csum = wred(m0 * c0v + m1 * c1v);
    float safe2 = fmaxf(cnt2, 1.f);
    float mc = csum / safe2;
    float vc = wred(m0 * (c0v - mc) * (c0v - mc) + m1 * (c1v - mc) * (c1v - mc)) / safe2;
    float mc_z = (cnt2 > 0.f) ? mc : 0.f;
    float sc_z = (cnt2 > 0.f) ? sqrtf(vc) : 0.f;
    s = mc_z + sc_z + 1e-4f;
    hist_mean = hsum * (1.f / (float)TLEN);
    sh[lane] = fminf(fmaxf(h0 / s, 0.f), 3.f);
    if (v1) sh[t1] = fminf(fmaxf(h1 / s, 0.f), 3.f);
  } else {
    // ---- waves 1-7: positional tables + date offsets ----
    for (int idx = tid - 64; idx < 640; idx += (NT - 64)) {
      int periods, freqs, row, col;
      if (idx < 88)       { periods = 10; freqs = 4; row = idx >> 3;        col = idx & 7; }
      else if (idx < 192) { periods = 12; freqs = 4; row = (idx - 88) >> 3; col = (idx - 88) & 7; }
      else if (idx < 576) { periods = 31; freqs = 6; int r2 = idx - 192; row = r2 / 12; col = r2 - row * 12; }
      else                { periods = 7;  freqs = 4; row = (idx - 576) >> 3; col = (idx - 576) & 7; }
      int jf = (col < freqs) ? col : (col - freqs);
      float pip = (float)(3.14159265358979323846 / (double)periods);
      float ang = pip * (float)(1 << jf) * ((float)row - 1.0f);
      pe[idx] = (col < freqs) ? sinf(ang) : cosf(ang);
    }
    int t = tid - 64;
    if (t < TLEN) {
      int yr99 = p.ts[((size_t)b * TLEN + (TLEN - 1)) * 4 + 0];
      const int* tsb = p.ts + ((size_t)b * TLEN + t) * 4;
      int dy = yr99 - tsb[0]; dy = dy < 0 ? 0 : (dy > 10 ? 10 : dy);
      datesu[t * 4 + 0] = (unsigned short)(dy * 8);
      datesu[t * 4 + 1] = (unsigned short)(88  + tsb[1] * 8);
      datesu[t * 4 + 2] = (unsigned short)(192 + tsb[2] * 12);
      datesu[t * 4 + 3] = (unsigned short)(576 + tsb[3] * 8);
    }
  }
  __syncthreads();

  // ---- build x: fp16 into R2[t][j] and transposed into R1[j][t] ----
  for (int idx = tid; idx < DM * TLEN; idx += NT) {
    int j = idx / TLEN;
    int t = idx - j * TLEN;
    float sv = sh[t];
    float v;
    if (j < DE) {
      v = fmaxf(fmaf(sv, p.w_np[j], p.b_np[j]), 0.f);
    } else {
      int jj = j - DE;
      float e1 = fmaxf(fmaf(sv, p.w_wp[jj], p.b_wp[jj]), 0.f);
      float pv;
      if (jj < 8)       pv = pe[datesu[t * 4 + 0] + jj];
      else if (jj < 16) pv = pe[datesu[t * 4 + 1] + (jj - 8)];
      else if (jj < 28) pv = pe[datesu[t * 4 + 2] + (jj - 16)];
      else              pv = pe[datesu[t * 4 + 3] + (jj - 28)];
      v = e1 + pv;
    }
    unsigned short hv = f2h(v);
    R1[j * OPLD + t] = hv;
    R2[t * OPLD + j] = hv;
  }
  if (tid < DM) {  // target row t=100
    int tk = p.task[b];
    float te = p.task_emb[tk * DE + (tid < DE ? tid : tid - DE)];
    float v = te;
    if (tid >= DE) {
      int jj = tid - DE;
      const int* tt = p.target_ts + (size_t)b * 5;
      int yr99 = p.ts[((size_t)b * TLEN + (TLEN - 1)) * 4 + 0];
      int dy = yr99 - tt[0]; dy = dy < 0 ? 0 : (dy > 10 ? 10 : dy);
      float qv;
      if (jj < 8)       qv = pe[dy * 8 + jj];
      else if (jj < 16) qv = pe[88  + tt[1] * 8  + (jj - 8)];
      else if (jj < 28) qv = pe[192 + tt[2] * 12 + (jj - 16)];
      else              qv = pe[576 + tt[3] * 8  + (jj - 28)];
      v = te + qv;
    }
    unsigned short hv = f2h(v);
    R1[tid * OPLD + (SEQ - 1)] = hv;
    R2[(SEQ - 1) * OPLD + tid] = hv;
  }
  __syncthreads();

  const int m16 = lane & 15;
  const int rowb = (lane >> 4) * 4;

  // ---- static per-wave N-blocked schedules (wave-uniform arithmetic) ----
  int Ar0, Anr, Ac0, Anc;
  if (wave < 6) { Ac0 = (wave / 3) * 2; Anc = 2; int sub = wave % 3; Ar0 = sub * 2; Anr = (sub < 2) ? 2 : 1; }
  else          { Ac0 = 4; Anc = 1; int sub = wave - 6; Ar0 = sub * 3; Anr = sub ? 2 : 3; }
  int Br0, Bnr, Bc0, Bnc;
  { int pr = wave >> 1; Bc0 = pr * 2; Bnc = (pr < 3) ? 2 : 1; int sub = wave & 1; Br0 = sub * 3; Bnr = sub ? 2 : 3; }
  int Cr0, Cnr, Cc0, Cnc;
  if (wave < 6) { Cc0 = (wave / 3) * 2; Cnc = 2; int sub = wave % 3; Cr0 = sub * 2; Cnr = (sub < 2) ? 2 : 3; }
  else          { Cc0 = 4; Cnc = 1; int sub = wave - 6; Cr0 = sub * 4; Cnr = sub ? 3 : 4; }

  #pragma unroll 1
  for (int rb = 0; rb < 2; ++rb) {
    const int base = rb * RB_SETS;
    const float* tb1 = p.tb1[rb]; const float* tb2 = p.tb2[rb];
    const float* cb1 = p.cb1[rb]; const float* cb2 = p.cb2[rb];

    // ---- A (SWAP): y1[c][j] = relu(tb1[j] + sum_t xT[c][t] tw1[t][j]);
    //      src R1(xT) -> dst R3(y1 as [c][j]) ----
    gemm_phase_nb<5, 4, true>(R1, p.wf, base + 0, lane, Ar0, Anr, Ac0, Anc,
      [&](int mt, int nt, f32x4 a) {
        int c  = mt * 16 + m16;
        int j0 = nt * 16 + rowb;
        if (c < DM && j0 < DM) {
          float4 b4 = *(const float4*)&tb1[j0];
          ushort4 hx;
          hx.x = f2h(fmaxf(a[0] + b4.x, 0.f));
          hx.y = f2h(fmaxf(a[1] + b4.y, 0.f));
          hx.z = f2h(fmaxf(a[2] + b4.z, 0.f));
          hx.w = f2h(fmaxf(a[3] + b4.w, 0.f));
          *(ushort4*)&R3[c * OPLD + j0] = hx;
        }
      });
    __syncthreads();

    // ---- B (no swap): x[t][c] += tb2[t] + sum_j y1[c][j] tw2[j][t];
    //      src R3(y1), x update in R2 ----
    gemm_phase_nb<7, 3, false>(R3, p.wf, base + 20, lane, Br0, Bnr, Bc0, Bnc,
      [&](int mt, int nt, f32x4 a) {
        int t  = nt * 16 + m16;
        int c0 = mt * 16 + rowb;
        if (t < SEQ && c0 < DM) {        // c0 mult of 4; DM mult of 4 -> no straddle
          float bias = tb2[t];
          ushort4 xo = *(const ushort4*)&R2[t * OPLD + c0];
          ushort4 hx;
          hx.x = f2h(h2f(xo.x) + a[0] + bias);
          hx.y = f2h(h2f(xo.y) + a[1] + bias);
          hx.z = f2h(h2f(xo.z) + a[2] + bias);
          hx.w = f2h(h2f(xo.w) + a[3] + bias);
          *(ushort4*)&R2[t * OPLD + c0] = hx;
        }
      });
    __syncthreads();

    // ---- C (SWAP): y2[t][j] = relu(cb1[j] + sum_c x[t][c] cw1[c][j]);
    //      src R2(x) -> dst R3(y2 as [t][j]) ----
    gemm_phase_nb<5, 3, true>(R2, p.wf, base + 41, lane, Cr0, Cnr, Cc0, Cnc,
      [&](int mt, int nt, f32x4 a) {
        int t  = mt * 16 + m16;
        int j0 = nt * 16 + rowb;
        if (t < SEQ && j0 < DM) {
          float4 b4 = *(const float4*)&cb1[j0];
          ushort4 hx;
          hx.x = f2h(fmaxf(a[0] + b4.x, 0.f));
          hx.y = f2h(fmaxf(a[1] + b4.y, 0.f));
          hx.z = f2h(fmaxf(a[2] + b4.z, 0.f));
          hx.w = f2h(fmaxf(a[3] + b4.w, 0.f));
          *(ushort4*)&R3[t * OPLD + j0] = hx;
        }
      });
    __syncthreads();

    // ---- D (SWAP): x[t][c] += cb2[c] + sum_j y2[t][j] cw2[j][c];
    //      src R3(y2) -> R2 rmw (ushort4) + R1 xT (4 scalar) ----
    gemm_phase_nb<5, 3, true>(R3, p.wf, base + 56, lane, Cr0, Cnr, Cc0, Cnc,
      [&](int mt, int nt, f32x4 a) {
        int t  = mt * 16 + m16;
        int c0 = nt * 16 + rowb;
        if (t < SEQ && c0 < DM) {
          float4 cb4 = *(const float4*)&cb2[c0];
          ushort4 xo = *(const ushort4*)&R2[t * OPLD + c0];
          ushort4 hx;
          hx.x = f2h(h2f(xo.x) + a[0] + cb4.x);
          hx.y = f2h(h2f(xo.y) + a[1] + cb4.y);
          hx.z = f2h(h2f(xo.z) + a[2] + cb4.z);
          hx.w = f2h(h2f(xo.w) + a[3] + cb4.w);
          *(ushort4*)&R2[t * OPLD + c0] = hx;
          R1[(c0 + 0) * OPLD + t] = hx.x;   // xT for next resblock's A
          R1[(c0 + 1) * OPLD + t] = hx.y;
          R1[(c0 + 2) * OPLD + t] = hx.z;
          R1[(c0 + 3) * OPLD + t] = hx.w;
        }
      });
    __syncthreads();
  }

  // ---- head (fp32 math on fp16 x) ----
  if (tid < DM) {
    float a = 0.f;
    for (int t = 0; t < SEQ; ++t) a = fmaf(h2f(R2[t * OPLD + tid]), p.wp_time[t], a);
    sh[tid] = (a + p.bp_time[0]) * p.w_head[tid];
  }
  __syncthreads();
  if (tid == 0) {
    float yv = 0.f;
    #pragma unroll 8
    for (int i = 0; i < DM; ++i) yv += sh[i];
    yv = fmaxf(yv + p.b_head[0], 0.f);
    p.out[b]      = yv * s + hist_mean;
    p.out[NB + b] = s;
  }
}

extern "C" void kernel_launch(void* const* d_in, const int* in_sizes, int n_in,
                              void* d_out, int out_size, void* d_ws, size_t ws_size,
                              hipStream_t stream) {
  (void)in_sizes; (void)n_in; (void)out_size; (void)ws_size;

  SetupParams sp;
  sp.tw1[0] = (const float*)d_in[9];  sp.tw2[0] = (const float*)d_in[11];
  sp.cw1[0] = (const float*)d_in[13]; sp.cw2[0] = (const float*)d_in[15];
  sp.tw1[1] = (const float*)d_in[17]; sp.tw2[1] = (const float*)d_in[19];
  sp.cw1[1] = (const float*)d_in[21]; sp.cw2[1] = (const float*)d_in[23];
  sp.ws = (unsigned*)d_ws;
  hipLaunchKernelGGL(setup_kernel, dim3(TOTAL_SETS), dim3(256), 0, stream, sp);

  Params p;
  p.history   = (const float*)d_in[0];
  p.ts        = (const int*)  d_in[1];
  p.target_ts = (const int*)  d_in[2];
  p.task      = (const int*)  d_in[3];
  p.w_np = (const float*)d_in[4];  p.b_np = (const float*)d_in[5];
  p.w_wp = (const float*)d_in[6];  p.b_wp = (const float*)d_in[7];
  p.task_emb = (const float*)d_in[8];
  p.tb1[0] = (const float*)d_in[10]; p.tb2[0] = (const float*)d_in[12];
  p.cb1[0] = (const float*)d_in[14]; p.cb2[0] = (const float*)d_in[16];
  p.tb1[1] = (const float*)d_in[18]; p.tb2[1] = (const float*)d_in[20];
  p.cb1[1] = (const float*)d_in[22]; p.cb2[1] = (const float*)d_in[24];
  p.wp_time = (const float*)d_in[25]; p.bp_time = (const float*)d_in[26];
  p.w_head  = (const float*)d_in[27]; p.b_head  = (const float*)d_in[28];
  p.wf  = (const uint4*)d_ws;
  p.out = (float*)d_out;
  hipLaunchKernelGGL(fpfn_kernel, dim3(NB), dim3(NT), 0, stream, p);
}